// Round 10
// baseline (130.881 us; speedup 1.0000x reference)
//
#include <hip/hip_runtime.h>
#include <hip/hip_bf16.h>

typedef _Float16 f16;
typedef _Float16 f16x2 __attribute__((ext_vector_type(2)));
typedef _Float16 f16x4 __attribute__((ext_vector_type(4)));
typedef _Float16 f16x8 __attribute__((ext_vector_type(8)));
typedef __fp16 h16x2 __attribute__((ext_vector_type(2)));
typedef float f32x4 __attribute__((ext_vector_type(4)));

#define DIM 1024
#define SEQ 2048
#define NB 2
#define NH 16
#define DHEAD 64
#define KVB 64
#define NT (SEQ / KVB)

// async global->LDS, 16B per lane. LDS dest = wave-uniform base (HW adds lane*16).
__device__ __forceinline__ void gl_lds16(const f16* g, f16* l) {
  __builtin_amdgcn_global_load_lds(
      (const __attribute__((address_space(1))) unsigned int*)(g),
      (__attribute__((address_space(3))) unsigned int*)(l), 16, 0, 0);
}

__device__ __forceinline__ f16x2 pkrtz(float a, float b) {
  h16x2 t = __builtin_amdgcn_cvt_pkrtz(a, b);
  return __builtin_bit_cast(f16x2, t);
}

// ---------------- RMS norm (f32) + cast to f16 ----------------
__global__ __launch_bounds__(256) void rms_cast_kernel(
    const float* __restrict__ x, const float* __restrict__ ctx,
    const float* __restrict__ gamma, f16* __restrict__ xn, f16* __restrict__ cn)
{
  int row = blockIdx.x;
  const float* src; f16* dst;
  if (row < NB * SEQ) { src = x + (size_t)row * DIM;              dst = xn + (size_t)row * DIM; }
  else                { src = ctx + (size_t)(row - NB*SEQ) * DIM; dst = cn + (size_t)(row - NB*SEQ) * DIM; }
  int t = threadIdx.x;
  float4 v = ((const float4*)src)[t];
  float ss = v.x*v.x + v.y*v.y + v.z*v.z + v.w*v.w;
  #pragma unroll
  for (int m = 1; m < 64; m <<= 1) ss += __shfl_xor(ss, m, 64);
  __shared__ float red[4];
  if ((t & 63) == 0) red[t >> 6] = ss;
  __syncthreads();
  float total = red[0] + red[1] + red[2] + red[3];
  float scale = 32.0f / fmaxf(sqrtf(total), 1e-12f);
  float4 gv = ((const float4*)gamma)[t];
  dst[4*t+0] = (f16)(v.x * scale * gv.x);
  dst[4*t+1] = (f16)(v.y * scale * gv.y);
  dst[4*t+2] = (f16)(v.z * scale * gv.z);
  dst[4*t+3] = (f16)(v.w * scale * gv.w);
}

// ---------------- fused weight transpose + cast (all 3 weights) ----------------
__global__ __launch_bounds__(256) void transpose_cast3_kernel(
    const float* __restrict__ Wq, const float* __restrict__ Wkv, const float* __restrict__ Wout,
    f16* __restrict__ WqT, f16* __restrict__ WkvT, f16* __restrict__ WoT)
{
  __shared__ float tile[32][33];
  int bx = blockIdx.x;
  const float* W; f16* Wt; int N, n0;
  if (bx < 32)      { W = Wq;   Wt = WqT;  N = 1024; n0 = bx * 32; }
  else if (bx < 96) { W = Wkv;  Wt = WkvT; N = 2048; n0 = (bx - 32) * 32; }
  else              { W = Wout; Wt = WoT;  N = 1024; n0 = (bx - 96) * 32; }
  int k0 = blockIdx.y * 32;
  int tx = threadIdx.x & 31, ty = threadIdx.x >> 5;
  #pragma unroll
  for (int i = 0; i < 32; i += 8)
    tile[ty + i][tx] = W[(size_t)(k0 + ty + i) * N + n0 + tx];
  __syncthreads();
  #pragma unroll
  for (int i = 0; i < 32; i += 8)
    Wt[(size_t)(n0 + ty + i) * 1024 + k0 + tx] = (f16)tile[tx][ty + i];
}

// ---------------- GEMM: C[M][N] = A[M][1024] * Bt[N][1024]^T ----------------
// m97-style: 128x128 tile, BK=64, 4 waves each 64x64 (4x4 acc), gl_lds w16
// staging into double-buffered linear LDS, ONE barrier per K-step.
template<int MODE>
__global__ __launch_bounds__(256, 2) void gemm_kernel(
    const f16* __restrict__ A, const f16* __restrict__ Bt,
    const float* __restrict__ scores,
    f16* __restrict__ o16a, f16* __restrict__ o16b, float* __restrict__ o32)
{
  __shared__ __align__(16) char L[65536];   // 2 bufs x (A 16KB + B 16KB)

  const int m0 = blockIdx.x * 128, n0 = blockIdx.y * 128;
  const int tid = threadIdx.x, lane = tid & 63, w = tid >> 6;
  const int wm = w >> 1, wn = w & 1;
  const int g = lane >> 4, c = lane & 15;

  const int sj = lane >> 3;                 // row offset within 8-row group
  const int sl = (lane & 7) ^ sj;           // pre-swizzled source chunk
  const f16* gA = A  + (size_t)(m0 + w*32 + sj) * 1024 + sl * 8;
  const f16* gB = Bt + (size_t)(n0 + w*32 + sj) * 1024 + sl * 8;
  const unsigned stA = w * 4096;
  const unsigned stB = 16384 + w * 4096;

  const unsigned swz = (c & 7) << 4;        // frag-read chunk XOR (bytes)

  f32x4 acc[4][4] = {};

#define GSTAGE(k0v, buf) {                                                      \
    _Pragma("unroll")                                                           \
    for (int i2 = 0; i2 < 4; i2++) {                                            \
      gl_lds16(gA + (size_t)(8*i2) * 1024 + (k0v), (f16*)(L + (buf) + stA + i2*1024)); \
      gl_lds16(gB + (size_t)(8*i2) * 1024 + (k0v), (f16*)(L + (buf) + stB + i2*1024)); \
    } }

  GSTAGE(0, 0)
  __syncthreads();

  for (int t = 0; t < 16; ++t) {
    const unsigned cur = (t & 1) ? 32768u : 0u;
    if (t + 1 < 16) GSTAGE((t + 1) * 64, cur ^ 32768u)
    #pragma unroll
    for (int kk = 0; kk < 2; kk++) {
      f16x8 af[4], bf[4];
      #pragma unroll
      for (int tm = 0; tm < 4; tm++)
        af[tm] = *(const f16x8*)(L + cur + (wm*64 + tm*16 + c)*128 + (((kk*4 + g) << 4) ^ swz));
      #pragma unroll
      for (int tn = 0; tn < 4; tn++)
        bf[tn] = *(const f16x8*)(L + cur + 16384 + (wn*64 + tn*16 + c)*128 + (((kk*4 + g) << 4) ^ swz));
      #pragma unroll
      for (int tm = 0; tm < 4; tm++)
        #pragma unroll
        for (int tn = 0; tn < 4; tn++)
          acc[tm][tn] = __builtin_amdgcn_mfma_f32_16x16x32_f16(af[tm], bf[tn], acc[tm][tn], 0, 0, 0);
    }
    __syncthreads();
  }
#undef GSTAGE

  #pragma unroll
  for (int tm = 0; tm < 4; tm++) {
    #pragma unroll
    for (int tn = 0; tn < 4; tn++) {
      int rg0 = m0 + wm*64 + tm*16 + g*4;          // 4 consecutive global rows
      int cg  = n0 + wn*64 + tn*16 + c;
      int b = rg0 >> 11, s0 = rg0 & 2047;
      if (MODE == 0) {
        int h = cg >> 6, d = cg & 63;
        #pragma unroll
        for (int r = 0; r < 4; r++)
          o16a[(((size_t)(b*NH + h))*SEQ + s0 + r)*DHEAD + d] =
              (f16)(acc[tm][tn][r] * 0.18033688011112043f);  // SCALE*log2(e)
      } else if (MODE == 1) {
        int hh = (cg & 1023) >> 6, d = cg & 63;
        if (cg < 1024) {
          #pragma unroll
          for (int r = 0; r < 4; r++)
            o16a[(((size_t)(b*NH + hh))*SEQ + s0 + r)*DHEAD + d] = (f16)acc[tm][tn][r];
        } else {
          float4 sc = *(const float4*)(scores + b*SEQ + s0);
          f16x4 pk;
          pk[0] = (f16)(acc[tm][tn][0] * sc.x);
          pk[1] = (f16)(acc[tm][tn][1] * sc.y);
          pk[2] = (f16)(acc[tm][tn][2] * sc.z);
          pk[3] = (f16)(acc[tm][tn][3] * sc.w);
          *(f16x4*)(o16b + (((size_t)(b*NH + hh))*DHEAD + d)*SEQ + s0) = pk;
        }
      } else {
        #pragma unroll
        for (int r = 0; r < 4; r++)
          o32[(size_t)(rg0 + r) * 1024 + cg] = acc[tm][tn][r];
      }
    }
  }
}

// ---------------- flash attention: 64 q/block, 4 waves (16q each), KVB=64, 4 blocks/CU ----
// S^T = K Q^T (per-lane softmax), O^T = V^T P^T.
// LDS (40960B = exactly 160KB/4):
//   slot s (s=0,1) at s*16384: K [64 kv][128B] + V^T [64 d][128B] at +8192,
//     16B-chunk XOR swizzle: physical chunk p = l ^ (row&7)
//   Pt: [32768, 40960)  per-wave P^T [16 q][128B], chunk XOR p = l ^ (q&7)
#define PT_OFF 32768

__global__ __launch_bounds__(256, 4) void attn_kernel(
    const f16* __restrict__ Q, const f16* __restrict__ K,
    const f16* __restrict__ Vt, f16* __restrict__ O)
{
  __shared__ __align__(16) char L[40960];

  const int bid = blockIdx.x;                        // 1024 blocks, 4/CU
  const int xcd = bid & 7, i = bid >> 3;             // i in 0..127
  const int bh  = xcd*4 + (i >> 5);                  // 4 heads per XCD
  const int q0  = (i & 31) * 64;
  const int tid = threadIdx.x, lane = tid & 63, w = tid >> 6;
  const int g = lane >> 4, c = lane & 15;

  const f16* Qb  = Q  + (size_t)bh * SEQ * DHEAD;
  const f16* Kb  = K  + (size_t)bh * SEQ * DHEAD;
  const f16* Vbt = Vt + (size_t)bh * DHEAD * SEQ;    // [d][kv]

  // Q fragments: wave owns 16 q rows; lane's q = q0 + w*16 + c
  f16x8 aq[2];
  {
    int qr = q0 + w*16 + c;
    aq[0] = *(const f16x8*)(Qb + (size_t)qr * DHEAD + g*8);
    aq[1] = *(const f16x8*)(Qb + (size_t)qr * DHEAD + 32 + g*8);
  }

  f32x4 oacc[4] = {};               // O^T: oacc[dt][r] = O[q=c][d=dt*16+4g+r]
  float mr = -1e30f, lr = 0.f;

  // staging: wave w stages K rows w*16..+15 and V^T rows w*16..+15 (4 gl_lds)
  const int sj = lane >> 3;                    // row within 1KB chunk (8 rows)
  const int sl = (lane & 7) ^ sj;              // pre-swizzled source chunk
  const f16* kgb0 = Kb  + (size_t)(w*16     + sj) * DHEAD + sl*8;
  const f16* kgb1 = Kb  + (size_t)(w*16 + 8 + sj) * DHEAD + sl*8;
  const f16* vgb0 = Vbt + (size_t)(w*16     + sj) * SEQ   + sl*8;
  const f16* vgb1 = Vbt + (size_t)(w*16 + 8 + sj) * SEQ   + sl*8;

  const unsigned ptb = PT_OFF + w*2048;            // wave-private [16 q][128B]
  const unsigned sw0 = ((g     ^ (c & 7)) << 4);   // K/V kc=0 chunk swizzle
  const unsigned sw1 = (((4+g) ^ (c & 7)) << 4);   // kc=1
  const unsigned cx  = (c & 7);                    // Pt chunk XOR

  f32x4 s[4];
  f16x4 pk[4];

#define STAGE(kv0v, slot) {                                                        \
    gl_lds16(kgb0 + (size_t)(kv0v)*DHEAD, (f16*)(L + (slot) + w*2048));            \
    gl_lds16(kgb1 + (size_t)(kv0v)*DHEAD, (f16*)(L + (slot) + w*2048 + 1024));     \
    gl_lds16(vgb0 + (kv0v),               (f16*)(L + (slot) + 8192 + w*2048));     \
    gl_lds16(vgb1 + (kv0v),               (f16*)(L + (slot) + 8192 + w*2048 + 1024)); }

#define QK_TILE(slot) {                                                            \
    _Pragma("unroll")                                                              \
    for (int ct = 0; ct < 4; ct++) {                                               \
      f16x8 k0 = *(const f16x8*)(L + (slot) + (ct*16 + c)*128 + sw0);              \
      f16x8 k1 = *(const f16x8*)(L + (slot) + (ct*16 + c)*128 + sw1);              \
      f32x4 z = {0.f, 0.f, 0.f, 0.f};                                              \
      z     = __builtin_amdgcn_mfma_f32_16x16x32_f16(k0, aq[0], z, 0, 0, 0);       \
      s[ct] = __builtin_amdgcn_mfma_f32_16x16x32_f16(k1, aq[1], z, 0, 0, 0);       \
    } }

#define SOFTMAX() {                                                                \
    float mx = -1e30f;                                                             \
    _Pragma("unroll")                                                              \
    for (int ct = 0; ct < 4; ct++)                                                 \
      mx = fmaxf(mx, fmaxf(fmaxf(s[ct][0], s[ct][1]), fmaxf(s[ct][2], s[ct][3]))); \
    mx = fmaxf(mx, __shfl_xor(mx, 16, 64));                                        \
    mx = fmaxf(mx, __shfl_xor(mx, 32, 64));                                        \
    if (!__all(mx <= mr + 8.f)) {                                                  \
      float mn = fmaxf(mr, mx);                                                    \
      float al = __builtin_amdgcn_exp2f(mr - mn);                                  \
      mr = mn; lr *= al;                                                           \
      _Pragma("unroll")                                                            \
      for (int dt = 0; dt < 4; dt++)                                               \
        { oacc[dt][0]*=al; oacc[dt][1]*=al; oacc[dt][2]*=al; oacc[dt][3]*=al; }    \
    }                                                                              \
    float rs = 0.f;                                                                \
    _Pragma("unroll")                                                              \
    for (int ct = 0; ct < 4; ct++) {                                               \
      float p0 = __builtin_amdgcn_exp2f(s[ct][0] - mr);                            \
      float p1 = __builtin_amdgcn_exp2f(s[ct][1] - mr);                            \
      float p2 = __builtin_amdgcn_exp2f(s[ct][2] - mr);                            \
      float p3 = __builtin_amdgcn_exp2f(s[ct][3] - mr);                            \
      rs += (p0 + p1) + (p2 + p3);                                                 \
      f16x2 lo = pkrtz(p0, p1), hi = pkrtz(p2, p3);                                \
      pk[ct] = __builtin_shufflevector(lo, hi, 0, 1, 2, 3);                        \
    }                                                                              \
    rs += __shfl_xor(rs, 16, 64); rs += __shfl_xor(rs, 32, 64);                    \
    lr += rs; }

// PWRITE: logical byte off = ct*32 + g*8 in row c -> chunk (ct*2 + (g>>1)) ^ cx
#define PWRITE() {                                                                 \
    _Pragma("unroll")                                                              \
    for (int ct = 0; ct < 4; ct++)                                                 \
      *(f16x4*)(L + ptb + c*128 + (((ct*2 + (g>>1)) ^ cx) << 4) + ((g & 1) << 3)) = pk[ct]; }

#define PV_TILE(slot) {                                                            \
    _Pragma("unroll")                                                              \
    for (int kc = 0; kc < 2; kc++) {                                               \
      f16x8 bp = *(const f16x8*)(L + ptb + c*128 + (((kc*4 + g) ^ cx) << 4));      \
      unsigned swc = kc ? sw1 : sw0;                                               \
      _Pragma("unroll")                                                            \
      for (int dt = 0; dt < 4; dt++) {                                             \
        f16x8 vf = *(const f16x8*)(L + (slot) + 8192 + (dt*16 + c)*128 + swc);     \
        oacc[dt] = __builtin_amdgcn_mfma_f32_16x16x32_f16(vf, bp, oacc[dt], 0, 0, 0); \
      }                                                                            \
    } }

  STAGE(0, 0);
  __syncthreads();

  for (int t = 0; t < NT; ++t) {
    const unsigned cur = (t & 1) ? 16384u : 0u;
    const unsigned nxt = cur ^ 16384u;
    if (t + 1 < NT) STAGE((t + 1) * KVB, nxt);
    __builtin_amdgcn_s_setprio(1);
    QK_TILE(cur);
    __builtin_amdgcn_s_setprio(0);
    SOFTMAX();
    PWRITE();
    __builtin_amdgcn_s_setprio(1);
    PV_TILE(cur);
    __builtin_amdgcn_s_setprio(0);
    __syncthreads();
  }

  // ---- epilogue: normalize, bounce via wave-private Pt, coalesced store ----
  {
    float inv = 1.0f / lr;
    #pragma unroll
    for (int dt = 0; dt < 4; dt++) {
      f16x4 ov;
      ov[0] = (f16)(oacc[dt][0] * inv);
      ov[1] = (f16)(oacc[dt][1] * inv);
      ov[2] = (f16)(oacc[dt][2] * inv);
      ov[3] = (f16)(oacc[dt][3] * inv);
      *(f16x4*)(L + ptb + c*128 + (((dt*2 + (g>>1)) ^ cx) << 4) + ((g & 1) << 3)) = ov;
    }
  }
  {
    const int b = bh >> 4, h = bh & 15;
    int ql = lane >> 2, chq = lane & 3;        // row 0..15, 32B chunk 0..3
    int sx = ql & 7;
    float4 a0 = *(const float4*)(L + ptb + ql*128 + (((chq*2)     ^ sx) << 4));
    float4 a1 = *(const float4*)(L + ptb + ql*128 + (((chq*2 + 1) ^ sx) << 4));
    f16* dst = O + ((size_t)(b*SEQ + q0 + w*16 + ql))*1024 + h*64 + chq*16;
    *(float4*)dst = a0;
    *(float4*)(dst + 8) = a1;
  }
#undef STAGE
#undef QK_TILE
#undef SOFTMAX
#undef PWRITE
#undef PV_TILE
}

extern "C" void kernel_launch(void* const* d_in, const int* in_sizes, int n_in,
                              void* d_out, int out_size, void* d_ws, size_t ws_size,
                              hipStream_t stream)
{
  const float* x      = (const float*)d_in[0];
  const float* ctx    = (const float*)d_in[1];
  const float* scores = (const float*)d_in[2];
  const float* gamma  = (const float*)d_in[4];
  const float* Wq     = (const float*)d_in[5];
  const float* Wkv    = (const float*)d_in[6];
  const float* Wout   = (const float*)d_in[7];
  float* out = (float*)d_out;

  char* ws = (char*)d_ws;
  const size_t MB = 1024 * 1024;
  f16* xn   = (f16*)(ws);
  f16* cn   = (f16*)(ws + 8*MB);
  f16* WqT  = (f16*)(ws + 16*MB);
  f16* WkvT = (f16*)(ws + 18*MB);
  f16* WoT  = (f16*)(ws + 22*MB);
  f16* qb   = (f16*)(ws + 24*MB);
  f16* kb   = (f16*)(ws + 32*MB);
  f16* vbT  = (f16*)(ws + 40*MB);   // [b*h][d][kv]
  f16* ao   = xn;

  rms_cast_kernel<<<NB*SEQ*2, 256, 0, stream>>>(x, ctx, gamma, xn, cn);
  transpose_cast3_kernel<<<dim3(128, 32), 256, 0, stream>>>(Wq, Wkv, Wout, WqT, WkvT, WoT);
  gemm_kernel<0><<<dim3(32, 8),  256, 0, stream>>>(xn, WqT,  nullptr, qb, nullptr, nullptr);
  gemm_kernel<1><<<dim3(32, 16), 256, 0, stream>>>(cn, WkvT, scores,  kb, vbT,     nullptr);
  attn_kernel<<<dim3(1024), 256, 0, stream>>>(qb, kb, vbT, ao);
  gemm_kernel<2><<<dim3(32, 8),  256, 0, stream>>>(ao, WoT,  nullptr, nullptr, nullptr, out);
}